// Round 1
// baseline (178.044 us; speedup 1.0000x reference)
//
#include <hip/hip_runtime.h>

// Problem: B=4096, S=256, F=64, K=16, L=256
//   logits[b,k,f] = sum_s x[b,s,f] * W[f,s,k]   (x NaN->0)
//   idx[b,f] = argmax_k logits[b,k,f]           (first max wins)
//   out[b,f,l] = snippet_list[f, idx[b,f], l]
constexpr int Bn = 4096, Sn = 256, Fn = 64, Kn = 16;

// W[f][s][k] -> Wt[s][f][k]  (1 MB, coalesced writes)
__global__ void transpose_w_kernel(const float* __restrict__ W, float* __restrict__ Wt) {
  int t = blockIdx.x * 256 + threadIdx.x;     // t == (s*64+f)*16+k
  int k = t & 15, f = (t >> 4) & 63, s = t >> 10;
  Wt[t] = W[(f * Sn + s) * Kn + k];
}

// Block = 256 threads (4 waves), covers 8 batches.
// wave w: bg = w&1 selects b-subgroup (4 b's), sh = w>>1 selects s-half.
// lane = f (0..63). Each thread: acc[4 b][16 k].
template <bool TR>
__global__ __launch_bounds__(256, 2) void fused_kernel(
    const float* __restrict__ x, const float* __restrict__ Wsrc,
    const float4* __restrict__ snip4, float4* __restrict__ out4) {
  __shared__ float red[2][4][16][64];  // 32 KB: [bg][i][k][f]
  __shared__ int idxs[8][64];          // 2 KB

  const int tid = threadIdx.x;
  const int lane = tid & 63;           // f
  const int w = tid >> 6;
  const int bg = w & 1;
  const int sh = w >> 1;
  const int bbase = blockIdx.x * 8;
  const int b0 = bbase + bg * 4;

  float acc[4][16];
#pragma unroll
  for (int i = 0; i < 4; ++i)
#pragma unroll
    for (int k = 0; k < 16; ++k) acc[i][k] = 0.f;

  const float* xp = x + (size_t)b0 * (Sn * Fn) + lane;
  const int s0 = sh * 128;
#pragma unroll 2
  for (int s = s0; s < s0 + 128; ++s) {
    float xs[4];
#pragma unroll
    for (int i = 0; i < 4; ++i) {
      float v = xp[(size_t)i * (Sn * Fn) + (size_t)s * Fn];
      xs[i] = (v == v) ? v : 0.f;  // NaN -> 0 per reference
    }
    float wv[16];
    if (TR) {
      // Wt[s][f][k]: 16 contiguous floats per lane, 4 KB contiguous per wave
      const float4* wp = reinterpret_cast<const float4*>(Wsrc + ((size_t)(s * Fn + lane) << 4));
#pragma unroll
      for (int j = 0; j < 4; ++j) {
        float4 q = wp[j];
        wv[4 * j + 0] = q.x; wv[4 * j + 1] = q.y; wv[4 * j + 2] = q.z; wv[4 * j + 3] = q.w;
      }
    } else {
      // direct W[f][s][k] fallback (uncoalesced across lanes, still correct)
      const float4* wp = reinterpret_cast<const float4*>(Wsrc + ((size_t)(lane * Sn + s) << 4));
#pragma unroll
      for (int j = 0; j < 4; ++j) {
        float4 q = wp[j];
        wv[4 * j + 0] = q.x; wv[4 * j + 1] = q.y; wv[4 * j + 2] = q.z; wv[4 * j + 3] = q.w;
      }
    }
#pragma unroll
    for (int i = 0; i < 4; ++i)
#pragma unroll
      for (int k = 0; k < 16; ++k)
        acc[i][k] = fmaf(xs[i], wv[k], acc[i][k]);
  }

  // combine s-halves: sh==1 waves dump, sh==0 waves add + argmax
  if (sh == 1) {
#pragma unroll
    for (int i = 0; i < 4; ++i)
#pragma unroll
      for (int k = 0; k < 16; ++k) red[bg][i][k][lane] = acc[i][k];
  }
  __syncthreads();
  if (sh == 0) {
#pragma unroll
    for (int i = 0; i < 4; ++i) {
#pragma unroll
      for (int k = 0; k < 16; ++k) acc[i][k] += red[bg][i][k][lane];
      float bv = acc[i][0];
      int bk = 0;
#pragma unroll
      for (int k = 1; k < 16; ++k)
        if (acc[i][k] > bv) { bv = acc[i][k]; bk = k; }  // strict >: first max wins
      idxs[bg * 4 + i][lane] = bk;
    }
  }
  __syncthreads();

  // gather: 8 b * 64 f = 512 rows of 1 KB; 1 row per wave-instr, coalesced
#pragma unroll 4
  for (int it = 0; it < 128; ++it) {
    int r = (it << 2) | w;
    int bi = r >> 6, f = r & 63;
    int kk = idxs[bi][f];
    float4 v = snip4[(size_t)((f * Kn + kk) << 6) + lane];
    out4[((size_t)(bbase + bi) * Fn + f) * 64 + lane] = v;
  }
}

extern "C" void kernel_launch(void* const* d_in, const int* in_sizes, int n_in,
                              void* d_out, int out_size, void* d_ws, size_t ws_size,
                              hipStream_t stream) {
  const float* x = (const float*)d_in[0];
  const float* W = (const float*)d_in[1];
  const float* snip = (const float*)d_in[2];
  float4* out4 = (float4*)d_out;
  const float4* snip4 = (const float4*)snip;

  const size_t wt_bytes = (size_t)Sn * Fn * Kn * sizeof(float);
  if (ws_size >= wt_bytes) {
    float* Wt = (float*)d_ws;
    transpose_w_kernel<<<(Sn * Fn * Kn) / 256, 256, 0, stream>>>(W, Wt);
    fused_kernel<true><<<Bn / 8, 256, 0, stream>>>(x, Wt, snip4, out4);
  } else {
    fused_kernel<false><<<Bn / 8, 256, 0, stream>>>(x, W, snip4, out4);
  }
}